// Round 4
// baseline (1196.436 us; speedup 1.0000x reference)
//
#include <hip/hip_runtime.h>

// Problem constants (from reference)
#define NBATCH 256
#define LI 2
#define LH 150
#define LQ 10
#define HS 128
#define WSD 128
#define KIT 40
#define AOUT 5

// LDS plane: 128x128 interior + 1-pixel zero halo, width padded to 132.
// Interior pixel (y,x) lives at lds[(y+1)*LCOLS + (x+1)].
#define LROWS 130
#define LCOLS 132
#define PLANE (LROWS * LCOLS)

// ---- Prep: collapse the linear hidden layer.
// W_eff[i,ky,kx] = sum_h r_w[h]*h_w[h,i,ky,kx],  b_eff = sum_h r_w[h]*h_b[h].
__global__ void prep_weff(const float* __restrict__ h_w,
                          const float* __restrict__ h_b,
                          const float* __restrict__ r_w,
                          float* __restrict__ w_eff) {
  const int t = threadIdx.x;
  if (t < 18) {
    const int i = t / 9, k = t % 9;
    double s = 0.0;
    for (int h = 0; h < LH; ++h)
      s += (double)r_w[h] * (double)h_w[(h * LI + i) * 9 + k];
    w_eff[t] = (float)s;
  } else if (t == 18) {
    double s = 0.0;
    for (int h = 0; h < LH; ++h)
      s += (double)r_w[h] * (double)h_b[h];
    w_eff[18] = (float)s;
  }
}

// Load a 6-wide row (16B-aligned base) with vectorized LDS reads.
__device__ __forceinline__ void load_row6(const float* __restrict__ p, float row[6]) {
  const float4 a = *reinterpret_cast<const float4*>(p);
  const float2 b = *reinterpret_cast<const float2*>(p + 4);
  row[0] = a.x; row[1] = a.y; row[2] = a.z; row[3] = a.w;
  row[4] = b.x; row[5] = b.y;
}

__device__ __forceinline__ void load_nb6(const float* __restrict__ p, float nb[6][6]) {
#pragma unroll
  for (int r = 0; r < 6; ++r) load_row6(p + r * LCOLS, nb[r]);
}

// One block per batch item; 1024 threads; each thread owns a 4x4 output tile.
// LDS: r-plane + v-plane (137 KB) -> 1 block/CU, 16 waves (4 waves/SIMD).
//
// SROA RULE (round-3 lesson): never form pointers to local arrays or select
// among them with ternaries — LLVM demotes the arrays to scratch (round 3:
// 66 MB scratch writeback, 3x VALU inflation, VGPR stuck at 64). All local
// array accesses below use compile-time-constant indices under full unroll.
__global__ __launch_bounds__(1024)
__attribute__((amdgpu_waves_per_eu(4, 4)))
void vin_main(const float* __restrict__ input,
              const int* __restrict__ coords,
              const float* __restrict__ q_w,
              const float* __restrict__ w_in,
              const float* __restrict__ fc_w,
              const float* __restrict__ w_eff,
              float* __restrict__ out) {
  extern __shared__ float lds[];
  float* rs = lds;           // r plane [LROWS][LCOLS], zero halo
  float* vs = lds + PLANE;   // v plane

  const int b = blockIdx.x;
  const int tid = threadIdx.x;
  const int ty = tid >> 5;             // 0..31
  const int tx = tid & 31;             // 0..31
  const int y0 = ty << 2;              // output rows y0..y0+3
  const int x0 = tx << 2;              // output cols x0..x0+3
  const int nb_off = y0 * LCOLS + x0;  // 6x6 window top-left (16B-aligned)

  // zero both planes (establishes the zero-padding halo)
  for (int i = tid; i < 2 * PLANE; i += 1024) lds[i] = 0.0f;
  __syncthreads();

  // stage input: ch0 -> rs interior, ch1 -> vs interior (coalesced)
  const float* in0 = input + (size_t)b * (LI * HS * WSD);
  const float* in1 = in0 + HS * WSD;
  for (int i = tid; i < HS * WSD; i += 1024) {
    const int y = i >> 7, x = i & (WSD - 1);
    rs[(y + 1) * LCOLS + (x + 1)] = in0[i];
    vs[(y + 1) * LCOLS + (x + 1)] = in1[i];
  }
  __syncthreads();

  // ---- r = conv(input, W_eff, pad=1) + b_eff ----
  float racc[4][4];
  {
    float nb0[6][6], nb1[6][6];
    load_nb6(rs + nb_off, nb0);
    load_nb6(vs + nb_off, nb1);
    const float beff = w_eff[18];
#pragma unroll
    for (int dy = 0; dy < 4; ++dy)
#pragma unroll
      for (int dx = 0; dx < 4; ++dx) racc[dy][dx] = beff;
#pragma unroll
    for (int kk = 0; kk < 9; ++kk) {
      const int ky = kk / 3, kx = kk % 3;
      const float w0 = w_eff[kk];
      const float w1 = w_eff[9 + kk];
#pragma unroll
      for (int dy = 0; dy < 4; ++dy)
#pragma unroll
        for (int dx = 0; dx < 4; ++dx)
          racc[dy][dx] += w0 * nb0[dy + ky][dx + kx] + w1 * nb1[dy + ky][dx + kx];
    }
  }
  __syncthreads();  // all input reads done before overwriting rs
#pragma unroll
  for (int dy = 0; dy < 4; ++dy)
#pragma unroll
    for (int dx = 0; dx < 4; ++dx)
      rs[(y0 + dy + 1) * LCOLS + (x0 + dx + 1)] = racc[dy][dx];
  __syncthreads();

  // r-neighborhood is invariant across all VI iterations: hold in registers
  // (36 VGPRs, persistent; constant-indexed everywhere).
  float nbr[6][6];
  load_nb6(rs + nb_off, nbr);

  // ---- v0 = max_c conv(r, q_w[c]) ---- (register-only compute from nbr)
  {
    float outv[4][4];
#pragma unroll
    for (int dy = 0; dy < 4; ++dy)
#pragma unroll
      for (int dx = 0; dx < 4; ++dx) outv[dy][dx] = -__builtin_inff();
#pragma unroll 2
    for (int c = 0; c < LQ; ++c) {
      const float* qc = q_w + c * 9;
#pragma unroll
      for (int dy = 0; dy < 4; ++dy) {
        float acc[4];
#pragma unroll
        for (int dx = 0; dx < 4; ++dx) acc[dx] = qc[0] * nbr[dy][dx];
#pragma unroll
        for (int kk = 1; kk < 9; ++kk) {
          const int ky = kk / 3, kx = kk % 3;
          const float q = qc[kk];
#pragma unroll
          for (int dx = 0; dx < 4; ++dx) acc[dx] += q * nbr[dy + ky][dx + kx];
        }
#pragma unroll
        for (int dx = 0; dx < 4; ++dx)
          outv[dy][dx] = fmaxf(outv[dy][dx], acc[dx]);
      }
    }
    // vs (input ch1) fully consumed before the pre-r-write barrier
#pragma unroll
    for (int dy = 0; dy < 4; ++dy)
#pragma unroll
      for (int dx = 0; dx < 4; ++dx)
        vs[(y0 + dy + 1) * LCOLS + (x0 + dx + 1)] = outv[dy][dx];
  }
  __syncthreads();

  // ---- K-1 = 39 value-iteration steps ----
  // Rolling 3-row v-window vwin[3][6]: rows dy, dy+1, dy+2 of the 6x6
  // neighborhood. Rotation is by VALUE copies with constant indices (SSA-
  // renamed under the full dy unroll) — no pointer selection (see SROA RULE).
#pragma unroll 1
  for (int it = 0; it < KIT - 1; ++it) {
    const float* vp = vs + nb_off;
    float vwin[3][6];
    load_row6(vp, vwin[0]);
    load_row6(vp + LCOLS, vwin[1]);
    float outv[4][4];
#pragma unroll
    for (int dy = 0; dy < 4; ++dy) {
      load_row6(vp + (dy + 2) * LCOLS, vwin[2]);
#pragma unroll
      for (int dx = 0; dx < 4; ++dx) outv[dy][dx] = -__builtin_inff();
#pragma unroll 2
      for (int c = 0; c < LQ; ++c) {
        const float* qc = q_w + c * 9;
        const float* wc = w_in + c * 9;
        float acc[4];
#pragma unroll
        for (int dx = 0; dx < 4; ++dx) acc[dx] = qc[0] * nbr[dy][dx];
#pragma unroll
        for (int kk = 1; kk < 9; ++kk) {
          const int ky = kk / 3, kx = kk % 3;
          const float q = qc[kk];
#pragma unroll
          for (int dx = 0; dx < 4; ++dx) acc[dx] += q * nbr[dy + ky][dx + kx];
        }
#pragma unroll
        for (int kk = 0; kk < 9; ++kk) {
          const int ky = kk / 3, kx = kk % 3;  // constant under unroll
          const float w = wc[kk];
#pragma unroll
          for (int dx = 0; dx < 4; ++dx) acc[dx] += w * vwin[ky][dx + kx];
        }
#pragma unroll
        for (int dx = 0; dx < 4; ++dx)
          outv[dy][dx] = fmaxf(outv[dy][dx], acc[dx]);
      }
      // rotate window down one row (value copies, constant indices)
#pragma unroll
      for (int j = 0; j < 6; ++j) { vwin[0][j] = vwin[1][j]; vwin[1][j] = vwin[2][j]; }
    }
    __syncthreads();  // all reads of vs done
#pragma unroll
    for (int dy = 0; dy < 4; ++dy)
#pragma unroll
      for (int dx = 0; dx < 4; ++dx)
        vs[(y0 + dy + 1) * LCOLS + (x0 + dx + 1)] = outv[dy][dx];
    __syncthreads();  // writes visible to next iteration
  }

  // ---- epilogue: final q at (sx,sy) only, then logits = fc_w @ q ----
  if (tid == 0) {
    const int sx = coords[b * 4 + 0];  // H index
    const int sy = coords[b * 4 + 1];  // W index
    const float* rb = rs + sx * LCOLS + sy;  // 3x3 window top-left (halo math)
    const float* vb2 = vs + sx * LCOLS + sy;
    float qv[LQ];
#pragma unroll 1
    for (int c = 0; c < LQ; ++c) {
      float s = 0.0f;
#pragma unroll
      for (int kk = 0; kk < 9; ++kk) {
        const int ky = kk / 3, kx = kk % 3;
        s += q_w[c * 9 + kk] * rb[ky * LCOLS + kx] +
             w_in[c * 9 + kk] * vb2[ky * LCOLS + kx];
      }
      qv[c] = s;
    }
#pragma unroll 1
    for (int a = 0; a < AOUT; ++a) {
      float s = 0.0f;
#pragma unroll
      for (int c = 0; c < LQ; ++c) s += fc_w[a * LQ + c] * qv[c];
      out[b * AOUT + a] = s;
    }
  }
}

extern "C" void kernel_launch(void* const* d_in, const int* in_sizes, int n_in,
                              void* d_out, int out_size, void* d_ws, size_t ws_size,
                              hipStream_t stream) {
  const float* input = (const float*)d_in[0];   // (B, 2, 128, 128)
  const int*   coords = (const int*)d_in[1];    // (B, 4)
  const float* h_w = (const float*)d_in[2];     // (150, 2, 3, 3)
  const float* h_b = (const float*)d_in[3];     // (150,)
  const float* r_w = (const float*)d_in[4];     // (1, 150, 1, 1)
  const float* q_w = (const float*)d_in[5];     // (10, 1, 3, 3)
  const float* w_in = (const float*)d_in[6];    // (10, 1, 3, 3)
  const float* fc_w = (const float*)d_in[7];    // (5, 10)
  float* out = (float*)d_out;                   // (B, 5)
  float* w_eff = (float*)d_ws;                  // 19 floats scratch

  const size_t smem = (size_t)2 * PLANE * sizeof(float);  // 137,280 B (>64KB)
  hipFuncSetAttribute(reinterpret_cast<const void*>(vin_main),
                      hipFuncAttributeMaxDynamicSharedMemorySize, (int)smem);

  prep_weff<<<1, 64, 0, stream>>>(h_w, h_b, r_w, w_eff);
  vin_main<<<NBATCH, 1024, smem, stream>>>(input, coords, q_w, w_in, fc_w, w_eff, out);
}

// Round 5
// 1045.864 us; speedup vs baseline: 1.1440x; 1.1440x over previous
//
#include <hip/hip_runtime.h>

// Problem constants (from reference)
#define NBATCH 256
#define LI 2
#define LH 150
#define LQ 10
#define HS 128
#define WSD 128
#define KIT 40
#define AOUT 5

// LDS plane: 128x128 interior + 1-pixel zero halo, width padded to 132.
// Interior pixel (y,x) lives at lds[(y+1)*LCOLS + (x+1)].
#define LROWS 130
#define LCOLS 132
#define PLANE (LROWS * LCOLS)

// ---- Prep: collapse the linear hidden layer.
// W_eff[i,ky,kx] = sum_h r_w[h]*h_w[h,i,ky,kx],  b_eff = sum_h r_w[h]*h_b[h].
__global__ void prep_weff(const float* __restrict__ h_w,
                          const float* __restrict__ h_b,
                          const float* __restrict__ r_w,
                          float* __restrict__ w_eff) {
  const int t = threadIdx.x;
  if (t < 18) {
    const int i = t / 9, k = t % 9;
    double s = 0.0;
    for (int h = 0; h < LH; ++h)
      s += (double)r_w[h] * (double)h_w[(h * LI + i) * 9 + k];
    w_eff[t] = (float)s;
  } else if (t == 18) {
    double s = 0.0;
    for (int h = 0; h < LH; ++h)
      s += (double)r_w[h] * (double)h_b[h];
    w_eff[18] = (float)s;
  }
}

// Load a 6-wide row (16B-aligned base) with vectorized LDS reads.
__device__ __forceinline__ void load_row6(const float* __restrict__ p, float row[6]) {
  const float4 a = *reinterpret_cast<const float4*>(p);
  const float2 b = *reinterpret_cast<const float2*>(p + 4);
  row[0] = a.x; row[1] = a.y; row[2] = a.z; row[3] = a.w;
  row[4] = b.x; row[5] = b.y;
}

// ROUND-4 LESSON: the previous structure relied on `#pragma unroll` of a
// large-body dy-loop; if that unroll doesn't happen, every nbr[dy+ky] /
// outv[dy] index is runtime -> SROA demotes the arrays to scratch
// (66 MB writeback footprint, ~3x VALU inflation, stuck at 64 VGPRs).
// The dy dimension is now HAND-UNROLLED via macros: every local-array
// index in this kernel is a compile-time literal under small unrolls only.

// One VI row (output row DY of the thread's 4x4 tile). rwin/vwin hold rows
// DY..DY+2 of the 6-row window. All indices literal.
#define VI_ROW(DY)                                                         \
  {                                                                        \
    _Pragma("unroll")                                                      \
    for (int dx = 0; dx < 4; ++dx) outv[DY][dx] = -__builtin_inff();       \
    _Pragma("unroll 2")                                                    \
    for (int c = 0; c < LQ; ++c) {                                         \
      const float* qc = q_w + c * 9;                                       \
      const float* wc = w_in + c * 9;                                      \
      float acc[4];                                                        \
      _Pragma("unroll")                                                    \
      for (int dx = 0; dx < 4; ++dx)                                       \
        acc[dx] = qc[0] * rwin[0][dx] + wc[0] * vwin[0][dx];               \
      _Pragma("unroll")                                                    \
      for (int kk = 1; kk < 9; ++kk) {                                     \
        const int ky = kk / 3, kx = kk % 3;                                \
        const float qv_ = qc[kk];                                          \
        const float wv_ = wc[kk];                                          \
        _Pragma("unroll")                                                  \
        for (int dx = 0; dx < 4; ++dx)                                     \
          acc[dx] += qv_ * rwin[ky][dx + kx] + wv_ * vwin[ky][dx + kx];    \
      }                                                                    \
      _Pragma("unroll")                                                    \
      for (int dx = 0; dx < 4; ++dx)                                       \
        outv[DY][dx] = fmaxf(outv[DY][dx], acc[dx]);                       \
    }                                                                      \
  }

// Shift both windows down one row and load plane row NEXTROW into slot 2.
#define WIN_SHIFT(NEXTROW)                                                 \
  {                                                                        \
    _Pragma("unroll")                                                      \
    for (int j = 0; j < 6; ++j) {                                          \
      rwin[0][j] = rwin[1][j]; rwin[1][j] = rwin[2][j];                    \
      vwin[0][j] = vwin[1][j]; vwin[1][j] = vwin[2][j];                    \
    }                                                                      \
    load_row6(rp + (NEXTROW) * LCOLS, rwin[2]);                            \
    load_row6(vp + (NEXTROW) * LCOLS, vwin[2]);                            \
  }

// One r-phase row: racc[DY][*] = b_eff + W_eff(ch0)*rwin + W_eff(ch1)*vwin.
#define R_ROW(DY)                                                          \
  {                                                                        \
    _Pragma("unroll")                                                      \
    for (int dx = 0; dx < 4; ++dx) racc[DY][dx] = beff;                    \
    _Pragma("unroll")                                                      \
    for (int kk = 0; kk < 9; ++kk) {                                       \
      const int ky = kk / 3, kx = kk % 3;                                  \
      const float w0 = w_eff[kk];                                          \
      const float w1 = w_eff[9 + kk];                                      \
      _Pragma("unroll")                                                    \
      for (int dx = 0; dx < 4; ++dx)                                       \
        racc[DY][dx] += w0 * rwin[ky][dx + kx] + w1 * vwin[ky][dx + kx];   \
    }                                                                      \
  }

// One block per batch item; 1024 threads; each thread owns a 4x4 tile.
// LDS: r-plane + v-plane (137 KB) -> 1 block/CU, 16 waves (4/SIMD).
// K-loop working set: rwin 18 + vwin 18 + outv 16 + acc 4 + addr ~6 ≈ 62
// regs — fits even a 64-VGPR budget with no spill.
__global__ __launch_bounds__(1024)
__attribute__((amdgpu_waves_per_eu(4, 4)))
void vin_main(const float* __restrict__ input,
              const int* __restrict__ coords,
              const float* __restrict__ q_w,
              const float* __restrict__ w_in,
              const float* __restrict__ fc_w,
              const float* __restrict__ w_eff,
              float* __restrict__ out) {
  extern __shared__ float lds[];
  float* rs = lds;           // ch0 input, then r plane
  float* vs = lds + PLANE;   // ch1 input, then v plane

  const int b = blockIdx.x;
  const int tid = threadIdx.x;
  const int ty = tid >> 5;             // 0..31
  const int tx = tid & 31;             // 0..31
  const int y0 = ty << 2;              // output rows y0..y0+3
  const int x0 = tx << 2;              // output cols x0..x0+3
  const int nb_off = y0 * LCOLS + x0;  // 6x6 window top-left (16B-aligned)
  const int wbase = (y0 + 1) * LCOLS + (x0 + 1);  // interior write base

  // zero both planes (establishes the zero halo)
  for (int i = tid; i < 2 * PLANE; i += 1024) lds[i] = 0.0f;
  __syncthreads();

  // stage input: ch0 -> rs interior, ch1 -> vs interior (float4 global loads)
  {
    const float4* in40 = (const float4*)(input + (size_t)b * (LI * HS * WSD));
    const float4* in41 = in40 + (HS * WSD / 4);
    for (int i = tid; i < HS * WSD / 4; i += 1024) {
      const int y = i >> 5, x4 = (i & 31) << 2;  // row, col of 4-wide group
      const float4 a = in40[i];
      const float4 c = in41[i];
      float* r0 = rs + (y + 1) * LCOLS + (x4 + 1);
      float* v0 = vs + (y + 1) * LCOLS + (x4 + 1);
      r0[0] = a.x; r0[1] = a.y; r0[2] = a.z; r0[3] = a.w;
      v0[0] = c.x; v0[1] = c.y; v0[2] = c.z; v0[3] = c.w;
    }
  }
  __syncthreads();

  // ---- r = conv(input, W_eff, pad=1) + b_eff  (rolling windows, hand-unrolled dy)
  {
    const float* rp = rs + nb_off;
    const float* vp = vs + nb_off;
    float rwin[3][6], vwin[3][6], racc[4][4];
    load_row6(rp, rwin[0]); load_row6(rp + LCOLS, rwin[1]); load_row6(rp + 2 * LCOLS, rwin[2]);
    load_row6(vp, vwin[0]); load_row6(vp + LCOLS, vwin[1]); load_row6(vp + 2 * LCOLS, vwin[2]);
    const float beff = w_eff[18];
    R_ROW(0) WIN_SHIFT(3) R_ROW(1) WIN_SHIFT(4) R_ROW(2) WIN_SHIFT(5) R_ROW(3)
    __syncthreads();  // all window reads of input done before overwriting
    // rs <- r, vs <- 0 (so K-loop iteration 1 yields exactly v0)
#pragma unroll
    for (int dy = 0; dy < 4; ++dy) {
      float* rw = rs + wbase + dy * LCOLS;
      float* vw = vs + wbase + dy * LCOLS;
      rw[0] = racc[dy][0]; rw[1] = racc[dy][1]; rw[2] = racc[dy][2]; rw[3] = racc[dy][3];
      vw[0] = 0.0f; vw[1] = 0.0f; vw[2] = 0.0f; vw[3] = 0.0f;
    }
  }
  __syncthreads();

  // ---- 40 identical VI iterations ----
  // it=0 (v==0): v1 = max_c [conv(r,q_w_c) + conv(0,w_c)] = max_c conv(r,q_w_c) = v0.
  // it=1..39: the reference's K-1 fori_loop steps.
#pragma unroll 1
  for (int it = 0; it < KIT; ++it) {
    const float* rp = rs + nb_off;
    const float* vp = vs + nb_off;
    float rwin[3][6], vwin[3][6], outv[4][4];
    load_row6(rp, rwin[0]); load_row6(rp + LCOLS, rwin[1]); load_row6(rp + 2 * LCOLS, rwin[2]);
    load_row6(vp, vwin[0]); load_row6(vp + LCOLS, vwin[1]); load_row6(vp + 2 * LCOLS, vwin[2]);
    VI_ROW(0) WIN_SHIFT(3) VI_ROW(1) WIN_SHIFT(4) VI_ROW(2) WIN_SHIFT(5) VI_ROW(3)
    __syncthreads();  // all reads of vs done
#pragma unroll
    for (int dy = 0; dy < 4; ++dy) {
      float* vw = vs + wbase + dy * LCOLS;
      vw[0] = outv[dy][0]; vw[1] = outv[dy][1]; vw[2] = outv[dy][2]; vw[3] = outv[dy][3];
    }
    __syncthreads();  // writes visible to next iteration
  }

  // ---- epilogue: final q at (sx,sy) only, then logits = fc_w @ q ----
  if (tid == 0) {
    const int sx = coords[b * 4 + 0];  // H index
    const int sy = coords[b * 4 + 1];  // W index
    const float* rb = rs + sx * LCOLS + sy;  // 3x3 window top-left (halo math)
    const float* vb2 = vs + sx * LCOLS + sy;
    float qv[LQ];
#pragma unroll 1
    for (int c = 0; c < LQ; ++c) {
      float s = 0.0f;
#pragma unroll
      for (int kk = 0; kk < 9; ++kk) {
        const int ky = kk / 3, kx = kk % 3;
        s += q_w[c * 9 + kk] * rb[ky * LCOLS + kx] +
             w_in[c * 9 + kk] * vb2[ky * LCOLS + kx];
      }
      qv[c] = s;
    }
#pragma unroll 1
    for (int a = 0; a < AOUT; ++a) {
      float s = 0.0f;
#pragma unroll
      for (int c = 0; c < LQ; ++c) s += fc_w[a * LQ + c] * qv[c];
      out[b * AOUT + a] = s;
    }
  }
}

extern "C" void kernel_launch(void* const* d_in, const int* in_sizes, int n_in,
                              void* d_out, int out_size, void* d_ws, size_t ws_size,
                              hipStream_t stream) {
  const float* input = (const float*)d_in[0];   // (B, 2, 128, 128)
  const int*   coords = (const int*)d_in[1];    // (B, 4)
  const float* h_w = (const float*)d_in[2];     // (150, 2, 3, 3)
  const float* h_b = (const float*)d_in[3];     // (150,)
  const float* r_w = (const float*)d_in[4];     // (1, 150, 1, 1)
  const float* q_w = (const float*)d_in[5];     // (10, 1, 3, 3)
  const float* w_in = (const float*)d_in[6];    // (10, 1, 3, 3)
  const float* fc_w = (const float*)d_in[7];    // (5, 10)
  float* out = (float*)d_out;                   // (B, 5)
  float* w_eff = (float*)d_ws;                  // 19 floats scratch

  const size_t smem = (size_t)2 * PLANE * sizeof(float);  // 137,280 B (>64KB)
  hipFuncSetAttribute(reinterpret_cast<const void*>(vin_main),
                      hipFuncAttributeMaxDynamicSharedMemorySize, (int)smem);

  prep_weff<<<1, 64, 0, stream>>>(h_w, h_b, r_w, w_eff);
  vin_main<<<NBATCH, 1024, smem, stream>>>(input, coords, q_w, w_in, fc_w, w_eff, out);
}